// Round 5
// baseline (6597.967 us; speedup 1.0000x reference)
//
#include <hip/hip_runtime.h>

typedef unsigned int u32;
typedef unsigned short u16;
typedef unsigned long long u64;
typedef __attribute__((ext_vector_type(8))) short short8;
typedef __attribute__((ext_vector_type(4))) float floatx4;

#define TT 1024
#define BIN_OFF 6553600
#define ACT_OFF 7864320

// scan5: per-wave 40 frags, F = kt*4 + gate; kt 0..5 (x + LOCAL h) in VGPRs (24 frags),
// kt 6..9 (REMOTE h) in LDS (16 frags).
#define F_REG5 24
#define F_LDS5 16

__device__ __forceinline__ u16 f2b(float f) {
  u32 u = __builtin_bit_cast(u32, f);
  u += 0x7fffu + ((u >> 16) & 1u);
  return (u16)(u >> 16);
}
__device__ __forceinline__ float sigmf(float x) { return 1.0f / (1.0f + __expf(-x)); }
__device__ __forceinline__ float tanhfast(float x) {
  x = fminf(x, 15.0f);
  float e = __expf(2.0f * x);
  return (e - 1.0f) / (e + 1.0f);
}

// ---------------- prep ----------------

__global__ void k_zero_flags(u32* __restrict__ flags) {
  if (threadIdx.x < 16) flags[threadIdx.x] = 0;
}
__global__ void k_prep_bias(const float* __restrict__ a, const float* __restrict__ b,
                            float* __restrict__ o) {
  int i = blockIdx.x * 256 + threadIdx.x;
  o[i] = a[i] + b[i];
}
__global__ void k_prep_afc(const float* __restrict__ wafc1, const float* __restrict__ waout,
                           u16* __restrict__ ob1, u16* __restrict__ ob2) {
  int r = blockIdx.x, k = threadIdx.x;
  if (r < 256) ob1[r * 256 + k] = f2b(wafc1[r * 256 + k]);
  else {
    int y = r - 256;
    ob2[y * 256 + k] = f2b(y < 8 ? waout[y * 256 + k] : 0.f);
  }
}
__global__ void k_prep_wcb(const float* __restrict__ wcont, const float* __restrict__ wbin,
                           u16* __restrict__ o) {
  int nrow = blockIdx.x, k = threadIdx.x;
  float v = 0.f;
  if (k < 264) {
    if (nrow < 50) v = wcont[nrow * 264 + k];
    else if (nrow < 60) v = wbin[(nrow - 50) * 264 + k];
  }
  o[nrow * 288 + k] = f2b(v);
}
__global__ void k_prep_xin(const float* __restrict__ x, u16* __restrict__ xin) {
  size_t idx = (size_t)blockIdx.x * 256 + threadIdx.x;
  size_t bt = idx >> 6;
  int d = (int)(idx & 63);
  int t = (int)(bt & 1023);
  float v = 0.f;
  if (d < 35) v = x[bt * 43 + d];
  else if (d < 43 && t > 0) v = x[(bt - 1) * 43 + d];
  xin[idx] = f2b(v);
}
// scan5 frag layout with K permuted per half:
// o[(((hf*8+wave)*40 + F)*64 + lane)*8 + j], F = kt*4 + gate;
// n = gate*256 + hf*128 + wave*16 + (lane&15);
// kt 0..1: x cols kt*32+kk (0 pad past 43); kt 2..5: h cols hf*128+(kt-2)*32+kk (LOCAL);
// kt 6..9: h cols (1-hf)*128+(kt-6)*32+kk (REMOTE).  kk = (lane>>4)*8 + j.
// grid 1280 x 256
__global__ void k_prep_wcatf3(const float* __restrict__ wih, const float* __restrict__ whh,
                              u16* __restrict__ o) {
  u32 idx = blockIdx.x * 256 + threadIdx.x;     // < 327680
  int j = idx & 7;
  int lane = (idx >> 3) & 63;
  u32 wf = idx >> 9;                             // (hf*8+wave)*40 + F, < 640
  int F = wf % 40, wv = wf / 40;
  int hf = wv >> 3, wave = wv & 7;
  int gate = F & 3, kt = F >> 2;
  int l15 = lane & 15, kq = lane >> 4;
  int kk = kq * 8 + j;
  int n = gate * 256 + hf * 128 + wave * 16 + l15;
  float v = 0.f;
  if (kt < 2) {
    int k = kt * 32 + kk;
    if (k < 43) v = wih[n * 43 + k];
  } else if (kt < 6) {
    int k = hf * 128 + (kt - 2) * 32 + kk;
    v = whh[n * 256 + k];
  } else {
    int k = (1 - hf) * 128 + (kt - 6) * 32 + kk;
    v = whh[n * 256 + k];
  }
  o[idx] = f2b(v);
}

// ---------------- LSTM scan v5: N-split pairs, overlapped exchange ----------------
// 16 WGs x 512 thr. WG g: pair p=g&7 (batch rows 16p..), half hf=g>>3 (h-cols
// hf*128..+127). All weights resident. Per step: phase A = MFMA on x + local h
// (register B-frags); per-wave acquire-spin on partner's counter; remote h loaded
// straight into A-fragments from a [m][col] global image (no LDS round trip);
// phase B = MFMA on remote h (LDS B-frags); elementwise; per-wave release.
__global__ __launch_bounds__(512)
void k_scan5(const u16* __restrict__ wcatf, const u16* __restrict__ xin,
             const float* __restrict__ bias, u16* __restrict__ hs,
             u16* __restrict__ xchg, u32* __restrict__ cnt) {
  __shared__ u16 wlds[8 * F_LDS5 * 512];  // 131072 B
  __shared__ u16 hsw[2 * 16 * 128];       //   8192 B (double-buffered swizzled local h)
  __shared__ u16 xt[2 * 16 * 64];         //   4096 B (double-buffered swizzled x)
  const int tid = threadIdx.x;            // total LDS 143360 B
  const int wave = tid >> 6, lane = tid & 63;
  const int l15 = lane & 15, kq = lane >> 4;
  const int g = blockIdx.x;
  const int p = g & 7, hf = g >> 3;
  const int partner = g ^ 8;              // same XCD under i%8 mapping
  const int b0 = p * 16;

  for (int i = tid; i < 4096; i += 512) hsw[i] = 0;

  const u16* wbase = wcatf + (size_t)((hf * 8 + wave) * 40) * 512;
  short8 breg[F_REG5];
#pragma unroll
  for (int F = 0; F < F_REG5; ++F)
    breg[F] = *(const short8*)(wbase + (size_t)F * 512 + lane * 8);
#pragma unroll
  for (int q = 0; q < F_LDS5; ++q)
    *(short8*)&wlds[(wave * F_LDS5 + q) * 512 + lane * 8] =
        *(const short8*)(wbase + (size_t)(F_REG5 + q) * 512 + lane * 8);
  float bias_r[4];
#pragma unroll
  for (int gate = 0; gate < 4; ++gate)
    bias_r[gate] = bias[gate * 256 + hf * 128 + wave * 16 + l15];
  {  // x_0 -> xt[0], swizzled
    int r = tid >> 5, jj = tid & 31, ch = jj >> 2;
    u32 v = *(const u32*)(xin + (size_t)(b0 + r) * TT * 64 + jj * 2);
    *(u32*)&xt[r * 64 + ((ch ^ (r & 7)) * 8 + (jj & 3) * 2)] = v;
  }
  const u16* xrp = xin + (size_t)(b0 + (tid >> 5)) * TT * 64 + (tid & 31) * 2;
  const int cl = wave * 16 + l15;        // local h col 0..127
  const int gcol = hf * 128 + cl;        // global h col
  u16* hp = hs + ((size_t)(b0 + kq * 4) * TT) * 256 + gcol;
  u16* mybuf = xchg + (size_t)g * 4096;           // 2 x 2048 u16 ([m][col] image)
  const u16* pbuf = xchg + (size_t)partner * 4096;

  float c_st[4] = {0.f, 0.f, 0.f, 0.f};
  u16 hreg[4];
  __syncthreads();

  for (int t = 0; t < TT; ++t) {
    const int cur = t & 1, nxt = cur ^ 1;
    // deferred hs stores for h_{t-1} (drain folds into this step's release)
    if (t > 0) {
#pragma unroll
      for (int rr = 0; rr < 4; ++rr)
        hp[(size_t)rr * TT * 256 + (size_t)(t - 1) * 256] = hreg[rr];
    }
    u32 xv = 0;
    if (t + 1 < TT) xv = *(const u32*)(xrp + (size_t)(t + 1) * 64);

    floatx4 acc[4];
#pragma unroll
    for (int i = 0; i < 4; ++i) acc[i] = (floatx4){0.f, 0.f, 0.f, 0.f};

    // ---- phase A: x chunks (kt 0..1), register B
#pragma unroll
    for (int kt = 0; kt < 2; ++kt) {
      int ch = kt * 4 + kq;
      short8 afr = *(const short8*)&xt[cur * 1024 + l15 * 64 + ((ch ^ (l15 & 7)) * 8)];
#pragma unroll
      for (int gate = 0; gate < 4; ++gate)
        acc[gate] = __builtin_amdgcn_mfma_f32_16x16x32_bf16(afr, breg[kt * 4 + gate],
                                                            acc[gate], 0, 0, 0);
    }
    if (t > 0) {
      // ---- phase A cont.: local h chunks (kt 2..5), register B
#pragma unroll
      for (int kt = 2; kt < 6; ++kt) {
        int ch = (kt - 2) * 4 + kq;
        short8 afr = *(const short8*)&hsw[cur * 2048 + l15 * 128 + ((ch ^ (l15 & 7)) * 8)];
#pragma unroll
        for (int gate = 0; gate < 4; ++gate)
          acc[gate] = __builtin_amdgcn_mfma_f32_16x16x32_bf16(afr, breg[kt * 4 + gate],
                                                              acc[gate], 0, 0, 0);
      }
      // ---- wait for partner h_{t-1}; acquire gives L1 inv for the data loads
      const u32 tgt = 8u * (u32)t;
      while (__hip_atomic_load(&cnt[partner], __ATOMIC_ACQUIRE,
                               __HIP_MEMORY_SCOPE_AGENT) < tgt) {}
      // ---- remote h straight into A-fragments ([m][col] image, parity (t-1)&1)
      const u16* pb = pbuf + (size_t)(nxt) * 2048;   // (t-1)&1 == nxt
      short8 ra[4];
#pragma unroll
      for (int c = 0; c < 4; ++c)
        ra[c] = *(const short8*)(pb + l15 * 128 + c * 32 + kq * 8);
      // ---- phase B: remote h chunks (kt 6..9), LDS B
#pragma unroll
      for (int kt = 6; kt < 10; ++kt) {
#pragma unroll
        for (int gate = 0; gate < 4; ++gate) {
          const int F = kt * 4 + gate;
          short8 bfr =
              *(const short8*)&wlds[(wave * F_LDS5 + (F - F_REG5)) * 512 + lane * 8];
          acc[gate] = __builtin_amdgcn_mfma_f32_16x16x32_bf16(ra[kt - 6], bfr,
                                                              acc[gate], 0, 0, 0);
        }
      }
    }

    // ---- elementwise (C-layout: row m=kq*4+rr, col gcol)
    u16* mb = mybuf + (size_t)cur * 2048;
#pragma unroll
    for (int rr = 0; rr < 4; ++rr) {
      float iv = sigmf(acc[0][rr] + bias_r[0]);
      float fv = sigmf(acc[1][rr] + bias_r[1]);
      float gv = tanhfast(acc[2][rr] + bias_r[2]);
      float ov = sigmf(acc[3][rr] + bias_r[3]);
      float cc = fv * c_st[rr] + iv * gv;
      c_st[rr] = cc;
      float h = ov * tanhfast(cc);
      u16 hb = f2b(h);
      hreg[rr] = hb;
      const int m = kq * 4 + rr;
      mb[m * 128 + cl] = hb;                         // [m][col] image for partner
    }
    // per-wave release: own stores drained by RELEASE ordering
    if (lane == 0)
      (void)__hip_atomic_fetch_add(&cnt[g], 1u, __ATOMIC_RELEASE,
                                   __HIP_MEMORY_SCOPE_AGENT);
    // local hsw[nxt] + xt[nxt] for next step
#pragma unroll
    for (int rr = 0; rr < 4; ++rr) {
      const int m = kq * 4 + rr;
      const int chw = cl >> 3;
      hsw[nxt * 2048 + m * 128 + ((chw ^ (m & 7)) * 8) + (cl & 7)] = hreg[rr];
    }
    if (t + 1 < TT) {
      int r = tid >> 5, jj = tid & 31, ch = jj >> 2;
      *(u32*)&xt[nxt * 1024 + r * 64 + ((ch ^ (r & 7)) * 8 + (jj & 3) * 2)] = xv;
    }
    __syncthreads();
  }
#pragma unroll
  for (int rr = 0; rr < 4; ++rr)
    hp[(size_t)rr * TT * 256 + (size_t)(TT - 1) * 256] = hreg[rr];
}

// ---------------- post heads ----------------

__global__ __launch_bounds__(256, 2)
void k_act(const u16* __restrict__ hs, const u16* __restrict__ wafc1,
           const u16* __restrict__ waout, const float* __restrict__ b_afc1,
           const float* __restrict__ b_aout, float* __restrict__ act) {
  __shared__ u16 a_sh[16 * 264];
  __shared__ u16 z_sh[16 * 264];
  __shared__ float sb1[256];
  const int tid = threadIdx.x;
  const int wave = tid >> 6, lane = tid & 63;
  const int l15 = lane & 15, kq = lane >> 4;
  const size_t bt0 = (size_t)blockIdx.x * 16;
  sb1[tid] = b_afc1[tid];
#pragma unroll
  for (int i = 0; i < 2; ++i) {
    int chunk = i * 256 + tid;
    int row = chunk >> 5, c = chunk & 31;
    *(uint4*)&a_sh[row * 264 + c * 8] = *(const uint4*)(hs + (bt0 + row) * 256 + c * 8);
  }
  __syncthreads();
  floatx4 acc[4];
#pragma unroll
  for (int nt = 0; nt < 4; ++nt) acc[nt] = (floatx4){0.f, 0.f, 0.f, 0.f};
#pragma unroll
  for (int kt = 0; kt < 8; ++kt) {
    short8 a = *(const short8*)&a_sh[l15 * 264 + kt * 32 + kq * 8];
#pragma unroll
    for (int nt = 0; nt < 4; ++nt) {
      int n = wave * 64 + nt * 16 + l15;
      short8 b = *(const short8*)(wafc1 + n * 256 + kt * 32 + kq * 8);
      acc[nt] = __builtin_amdgcn_mfma_f32_16x16x32_bf16(a, b, acc[nt], 0, 0, 0);
    }
  }
#pragma unroll
  for (int nt = 0; nt < 4; ++nt) {
    int n = wave * 64 + nt * 16 + l15;
    float bb = sb1[n];
#pragma unroll
    for (int r = 0; r < 4; ++r) {
      float v = acc[nt][r] + bb;
      v = v > 0.f ? v : 0.f;
      z_sh[(kq * 4 + r) * 264 + n] = f2b(v);
    }
  }
  __syncthreads();
  if (wave == 0) {
    floatx4 a2 = (floatx4){0.f, 0.f, 0.f, 0.f};
#pragma unroll
    for (int kt = 0; kt < 8; ++kt) {
      short8 a = *(const short8*)&z_sh[l15 * 264 + kt * 32 + kq * 8];
      short8 b = *(const short8*)(waout + l15 * 256 + kt * 32 + kq * 8);
      a2 = __builtin_amdgcn_mfma_f32_16x16x32_bf16(a, b, a2, 0, 0, 0);
    }
    if (l15 < 8) {
      float bb = b_aout[l15];
#pragma unroll
      for (int r = 0; r < 4; ++r)
        act[(bt0 + (size_t)(kq * 4 + r)) * 8 + l15] = a2[r] + bb;
    }
  }
}

__global__ __launch_bounds__(256, 2)
void k_cb(const u16* __restrict__ hs, const float* __restrict__ x,
          const u16* __restrict__ wcb, const float* __restrict__ b_cont,
          const float* __restrict__ b_bin, float* __restrict__ dout) {
  __shared__ u16 a_sh[16 * 296];
  const int tid = threadIdx.x;
  const int wave = tid >> 6, lane = tid & 63;
  const int l15 = lane & 15, kq = lane >> 4;
  const size_t bt0 = (size_t)blockIdx.x * 16;
#pragma unroll
  for (int i = 0; i < 2; ++i) {
    int chunk = i * 256 + tid;
    int row = chunk >> 5, c = chunk & 31;
    *(uint4*)&a_sh[row * 296 + c * 8] = *(const uint4*)(hs + (bt0 + row) * 256 + c * 8);
  }
  if (tid < 128) {
    int m = tid >> 3, j = tid & 7;
    a_sh[m * 296 + 256 + j] = f2b(x[(bt0 + m) * 43 + 35 + j]);
  }
  for (int i = tid; i < 384; i += 256) {
    int m = i / 24, jj = i % 24;
    a_sh[m * 296 + 264 + jj] = 0;
  }
  __syncthreads();
  const int n = wave * 16 + l15;
  floatx4 acc = (floatx4){0.f, 0.f, 0.f, 0.f};
#pragma unroll
  for (int kt = 0; kt < 9; ++kt) {
    short8 a = *(const short8*)&a_sh[l15 * 296 + kt * 32 + kq * 8];
    short8 b = *(const short8*)(wcb + n * 288 + kt * 32 + kq * 8);
    acc = __builtin_amdgcn_mfma_f32_16x16x32_bf16(a, b, acc, 0, 0, 0);
  }
  if (n < 50) {
    float bb = b_cont[n];
#pragma unroll
    for (int r = 0; r < 4; ++r)
      dout[(bt0 + (size_t)(kq * 4 + r)) * 50 + n] = acc[r] + bb;
  } else if (n < 60) {
    float bb = b_bin[n - 50];
#pragma unroll
    for (int r = 0; r < 4; ++r)
      dout[BIN_OFF + (bt0 + (size_t)(kq * 4 + r)) * 10 + (n - 50)] = sigmf(acc[r] + bb);
  }
}

// ---------------- launch ----------------
extern "C" void kernel_launch(void* const* d_in, const int* in_sizes, int n_in,
                              void* d_out, int out_size, void* d_ws, size_t ws_size,
                              hipStream_t stream) {
  const float* x      = (const float*)d_in[0];
  const float* W_ih   = (const float*)d_in[1];
  const float* W_hh   = (const float*)d_in[2];
  const float* b_ih   = (const float*)d_in[3];
  const float* b_hh   = (const float*)d_in[4];
  const float* W_afc1 = (const float*)d_in[5];
  const float* b_afc1 = (const float*)d_in[6];
  const float* W_aout = (const float*)d_in[7];
  const float* b_aout = (const float*)d_in[8];
  const float* W_cont = (const float*)d_in[9];
  const float* b_cont = (const float*)d_in[10];
  const float* W_bin  = (const float*)d_in[11];
  const float* b_bin  = (const float*)d_in[12];
  float* outf = (float*)d_out;
  char* ws = (char*)d_ws;

  u16*   wcatf  = (u16*)(ws);                    //    655,360 B
  float* bias   = (float*)(ws + 655360);         //      4,096 B
  u16*   wafc1b = (u16*)(ws + 659456);           //    131,072 B
  u16*   waoutb = (u16*)(ws + 790528);           //      8,192 B
  u16*   wcbb   = (u16*)(ws + 798720);           //     36,864 B
  u16*   xchg   = (u16*)(ws + 835584);           //    131,072 B
  u32*   flags  = (u32*)(ws + 966656);           //      4,096 B
  u16*   xin    = (u16*)(ws + 970752);           // 16,777,216 B
  u16*   hs     = (u16*)(ws + 17747968);         // 67,108,864 B (total ~84.9 MB)

  hipLaunchKernelGGL(k_prep_wcatf3, dim3(1280), dim3(256), 0, stream, W_ih, W_hh, wcatf);
  hipLaunchKernelGGL(k_zero_flags, dim3(1), dim3(64), 0, stream, flags);
  hipLaunchKernelGGL(k_prep_bias, dim3(4), dim3(256), 0, stream, b_ih, b_hh, bias);
  hipLaunchKernelGGL(k_prep_afc, dim3(272), dim3(256), 0, stream, W_afc1, W_aout, wafc1b, waoutb);
  hipLaunchKernelGGL(k_prep_wcb, dim3(64), dim3(288), 0, stream, W_cont, W_bin, wcbb);
  hipLaunchKernelGGL(k_prep_xin, dim3(32768), dim3(256), 0, stream, x, xin);
  hipLaunchKernelGGL(k_scan5, dim3(16), dim3(512), 0, stream, wcatf, xin, bias, hs, xchg, flags);
  hipLaunchKernelGGL(k_act, dim3(8192), dim3(256), 0, stream, hs, wafc1b, waoutb, b_afc1, b_aout, outf + ACT_OFF);
  hipLaunchKernelGGL(k_cb, dim3(8192), dim3(256), 0, stream, hs, x, wcbb, b_cont, b_bin, outf);
}

// Round 6
// 4017.679 us; speedup vs baseline: 1.6422x; 1.6422x over previous
//
#include <hip/hip_runtime.h>

typedef unsigned int u32;
typedef unsigned short u16;
typedef unsigned long long u64;
typedef __attribute__((ext_vector_type(8))) short short8;
typedef __attribute__((ext_vector_type(4))) float floatx4;

#define TT 1024
#define BIN_OFF 6553600
#define ACT_OFF 7864320

// scan6: per-wave 40 frags, F = kt*4 + gate; kt 0..7 (x + local h + first half of
// remote h) in VGPRs (32 frags = 128 VGPR), kt 8..9 (rest of remote h) in LDS.
#define F_REG6 32
#define F_LDS6 8

__device__ __forceinline__ u16 f2b(float f) {
  u32 u = __builtin_bit_cast(u32, f);
  u += 0x7fffu + ((u >> 16) & 1u);
  return (u16)(u >> 16);
}
__device__ __forceinline__ float sigmf(float x) { return 1.0f / (1.0f + __expf(-x)); }
__device__ __forceinline__ float tanhfast(float x) {
  x = fminf(x, 15.0f);
  float e = __expf(2.0f * x);
  return (e - 1.0f) / (e + 1.0f);
}

// ---------------- prep ----------------

__global__ void k_zero_flags(u32* __restrict__ flags) {
  if (threadIdx.x < 16) flags[threadIdx.x] = 0;
}
__global__ void k_prep_bias(const float* __restrict__ a, const float* __restrict__ b,
                            float* __restrict__ o) {
  int i = blockIdx.x * 256 + threadIdx.x;
  o[i] = a[i] + b[i];
}
__global__ void k_prep_afc(const float* __restrict__ wafc1, const float* __restrict__ waout,
                           u16* __restrict__ ob1, u16* __restrict__ ob2) {
  int r = blockIdx.x, k = threadIdx.x;
  if (r < 256) ob1[r * 256 + k] = f2b(wafc1[r * 256 + k]);
  else {
    int y = r - 256;
    ob2[y * 256 + k] = f2b(y < 8 ? waout[y * 256 + k] : 0.f);
  }
}
__global__ void k_prep_wcb(const float* __restrict__ wcont, const float* __restrict__ wbin,
                           u16* __restrict__ o) {
  int nrow = blockIdx.x, k = threadIdx.x;
  float v = 0.f;
  if (k < 264) {
    if (nrow < 50) v = wcont[nrow * 264 + k];
    else if (nrow < 60) v = wbin[(nrow - 50) * 264 + k];
  }
  o[nrow * 288 + k] = f2b(v);
}
__global__ void k_prep_xin(const float* __restrict__ x, u16* __restrict__ xin) {
  size_t idx = (size_t)blockIdx.x * 256 + threadIdx.x;
  size_t bt = idx >> 6;
  int d = (int)(idx & 63);
  int t = (int)(bt & 1023);
  float v = 0.f;
  if (d < 35) v = x[bt * 43 + d];
  else if (d < 43 && t > 0) v = x[(bt - 1) * 43 + d];
  xin[idx] = f2b(v);
}
// frag layout with K permuted per half (same as scan5):
// o[(((hf*8+wave)*40 + F)*64 + lane)*8 + j], F = kt*4 + gate;
// n = gate*256 + hf*128 + wave*16 + (lane&15);
// kt 0..1: x cols; kt 2..5: LOCAL h cols hf*128+..; kt 6..9: REMOTE h cols.
// grid 1280 x 256
__global__ void k_prep_wcatf3(const float* __restrict__ wih, const float* __restrict__ whh,
                              u16* __restrict__ o) {
  u32 idx = blockIdx.x * 256 + threadIdx.x;     // < 327680
  int j = idx & 7;
  int lane = (idx >> 3) & 63;
  u32 wf = idx >> 9;                             // (hf*8+wave)*40 + F, < 640
  int F = wf % 40, wv = wf / 40;
  int hf = wv >> 3, wave = wv & 7;
  int gate = F & 3, kt = F >> 2;
  int l15 = lane & 15, kq = lane >> 4;
  int kk = kq * 8 + j;
  int n = gate * 256 + hf * 128 + wave * 16 + l15;
  float v = 0.f;
  if (kt < 2) {
    int k = kt * 32 + kk;
    if (k < 43) v = wih[n * 43 + k];
  } else if (kt < 6) {
    int k = hf * 128 + (kt - 2) * 32 + kk;
    v = whh[n * 256 + k];
  } else {
    int k = (1 - hf) * 128 + (kt - 6) * 32 + kk;
    v = whh[n * 256 + k];
  }
  o[idx] = f2b(v);
}

// ---------------- LSTM scan v6 ----------------
// 16 WGs x 512 thr, __launch_bounds__(512,2) -> 256 VGPR budget. WG g: pair
// p=g&7 (batch rows 16p..), half hf=g>>3 (h-cols hf*128..+127). Weights truly
// resident: 32 frags/wave pinned in VGPRs (non-restrict pointer + in-loop
// memory-clobber asm make remat illegal), 8 frags in LDS. Per step:
//   phase A: MFMA x + local h (register B) while partner's flag (set one step
//   ago) is pre-polled by tid0 -> B1 -> coalesced u64 image load + LDS scatter
//   -> B2 -> phase B: MFMA remote h -> elementwise -> coalesced image store,
//   vmcnt drain, B3, tid0 release. hs written via deferred LDS->global copy.
__global__ __launch_bounds__(512, 2)
void k_scan6(u16* wcatf_, const u16* __restrict__ xin,
             const float* __restrict__ bias, u16* __restrict__ hs,
             u16* __restrict__ xchg, u32* __restrict__ cnt) {
  __shared__ u16 wlds[8 * F_LDS6 * 512];  // 65536 B
  __shared__ u16 rhsw[16 * 128];          //  4096 B (swizzled remote h)
  __shared__ u16 hsw[2 * 16 * 128];       //  8192 B (double-buffered swizzled local h)
  __shared__ u16 xt[2 * 16 * 64];         //  4096 B (double-buffered swizzled x)
  const int tid = threadIdx.x;            // total LDS 81920 B
  const int wave = tid >> 6, lane = tid & 63;
  const int l15 = lane & 15, kq = lane >> 4;
  const int g = blockIdx.x;
  const int p = g & 7, hf = g >> 3;
  const int partner = g ^ 8;
  const int b0 = p * 16;

  const u16* wbase = wcatf_ + (size_t)((hf * 8 + wave) * 40) * 512;
  short8 breg[F_REG6];
#pragma unroll
  for (int F = 0; F < F_REG6; ++F)
    breg[F] = *(const short8*)(wbase + (size_t)F * 512 + lane * 8);
#pragma unroll
  for (int q = 0; q < F_LDS6; ++q)
    *(short8*)&wlds[(wave * F_LDS6 + q) * 512 + lane * 8] =
        *(const short8*)(wbase + (size_t)(F_REG6 + q) * 512 + lane * 8);
  float bias_r[4];
#pragma unroll
  for (int gate = 0; gate < 4; ++gate)
    bias_r[gate] = bias[gate * 256 + hf * 128 + wave * 16 + l15];
  {  // x_0 -> xt[0], swizzled
    int r = tid >> 5, jj = tid & 31, ch = jj >> 2;
    u32 v = *(const u32*)(xin + (size_t)(b0 + r) * TT * 64 + jj * 2);
    *(u32*)&xt[r * 64 + ((ch ^ (r & 7)) * 8 + (jj & 3) * 2)] = v;
  }
  const u16* xrp = xin + (size_t)(b0 + (tid >> 5)) * TT * 64 + (tid & 31) * 2;
  const int cl = wave * 16 + l15;        // local h col 0..127
  u64* myimg = (u64*)xchg + (size_t)g * 1024;          // 2 parities x 512 u64
  const u64* pimg = (u64*)xchg + (size_t)partner * 1024;
  // deferred hs copy mapping: row m = tid>>5, 4 cols starting c4 = (tid&31)*4
  const int cm = tid >> 5;
  const int c4 = (tid & 31) * 4;
  const int clds = cm * 128 + (((c4 >> 3) ^ (cm & 7)) << 3) + (c4 & 7);
  u16* hgp = hs + (size_t)(b0 + cm) * TT * 256 + hf * 128 + c4;
  // image scatter mapping (reader side)
  const int rcol = (tid >> 6) * 16 + (tid & 15);
  const int rm0 = ((tid >> 4) & 3) * 4;

  float c_st[4] = {0.f, 0.f, 0.f, 0.f};
  __syncthreads();

  for (int t = 0; t < TT; ++t) {
    const int cur = t & 1, nxt = cur ^ 1;
    asm volatile("" ::: "memory");      // pin: weight loads cannot remat past this
    u32 f0 = 0;
    if (tid == 0 && t > 0)              // pre-poll (partner released 1 step ago)
      f0 = __hip_atomic_load(&cnt[partner], __ATOMIC_ACQUIRE, __HIP_MEMORY_SCOPE_AGENT);
    if (t > 0) {                        // deferred coalesced hs copy of h_{t-1}
      u64 hv = *(const u64*)&hsw[cur * 2048 + clds];
      *(u64*)(hgp + (size_t)(t - 1) * 256) = hv;
    }
    u32 xv = 0;
    if (t + 1 < TT) xv = *(const u32*)(xrp + (size_t)(t + 1) * 64);

    floatx4 acc[4];
#pragma unroll
    for (int i = 0; i < 4; ++i) acc[i] = (floatx4){0.f, 0.f, 0.f, 0.f};

    // ---- phase A: x chunks (kt 0..1), register B
#pragma unroll
    for (int kt = 0; kt < 2; ++kt) {
      int ch = kt * 4 + kq;
      short8 afr = *(const short8*)&xt[cur * 1024 + l15 * 64 + ((ch ^ (l15 & 7)) * 8)];
#pragma unroll
      for (int gate = 0; gate < 4; ++gate)
        acc[gate] = __builtin_amdgcn_mfma_f32_16x16x32_bf16(afr, breg[kt * 4 + gate],
                                                            acc[gate], 0, 0, 0);
    }
    if (t > 0) {
      // ---- phase A cont.: local h chunks (kt 2..5), register B
#pragma unroll
      for (int kt = 2; kt < 6; ++kt) {
        int ch = (kt - 2) * 4 + kq;
        short8 afr =
            *(const short8*)&hsw[cur * 2048 + l15 * 128 + ((ch ^ (l15 & 7)) * 8)];
#pragma unroll
        for (int gate = 0; gate < 4; ++gate)
          acc[gate] = __builtin_amdgcn_mfma_f32_16x16x32_bf16(afr, breg[kt * 4 + gate],
                                                              acc[gate], 0, 0, 0);
      }
      // ---- wait for partner h_{t-1} (usually already set)
      if (tid == 0) {
        while (f0 < (u32)t)
          f0 = __hip_atomic_load(&cnt[partner], __ATOMIC_ACQUIRE,
                                 __HIP_MEMORY_SCOPE_AGENT);
      }
      __syncthreads();   // B1
      // ---- coalesced remote image load (parity (t-1)&1 == nxt) + LDS scatter
      u64 pv = __hip_atomic_load(pimg + (size_t)nxt * 512 + tid,
                                 __ATOMIC_RELAXED, __HIP_MEMORY_SCOPE_AGENT);
#pragma unroll
      for (int rr = 0; rr < 4; ++rr) {
        const int m = rm0 + rr;
        rhsw[m * 128 + (((rcol >> 3) ^ (m & 7)) << 3) + (rcol & 7)] =
            (u16)(pv >> (16 * rr));
      }
      __syncthreads();   // B2
      // ---- phase B: remote h chunks (kt 6..7 register B, kt 8..9 LDS B)
#pragma unroll
      for (int kt = 6; kt < 10; ++kt) {
        int ch = (kt - 6) * 4 + kq;
        short8 afr = *(const short8*)&rhsw[l15 * 128 + ((ch ^ (l15 & 7)) * 8)];
#pragma unroll
        for (int gate = 0; gate < 4; ++gate) {
          short8 bfr;
          if (kt < 8) bfr = breg[kt * 4 + gate];
          else
            bfr = *(const short8*)&wlds[(wave * F_LDS6 + (kt - 8) * 4 + gate) * 512 +
                                        lane * 8];
          acc[gate] = __builtin_amdgcn_mfma_f32_16x16x32_bf16(afr, bfr, acc[gate],
                                                              0, 0, 0);
        }
      }
    }

    // ---- elementwise (C-layout: row m=kq*4+rr, col cl local / hf*128+cl global)
    u64 pk = 0;
#pragma unroll
    for (int rr = 0; rr < 4; ++rr) {
      float iv = sigmf(acc[0][rr] + bias_r[0]);
      float fv = sigmf(acc[1][rr] + bias_r[1]);
      float gv = tanhfast(acc[2][rr] + bias_r[2]);
      float ov = sigmf(acc[3][rr] + bias_r[3]);
      float cc = fv * c_st[rr] + iv * gv;
      c_st[rr] = cc;
      float h = ov * tanhfast(cc);
      u16 hb = f2b(h);
      pk |= ((u64)hb) << (16 * rr);
      const int m = kq * 4 + rr;
      hsw[nxt * 2048 + m * 128 + (((cl >> 3) ^ (m & 7)) << 3) + (cl & 7)] = hb;
    }
    __hip_atomic_store(myimg + (size_t)cur * 512 + tid, pk,
                       __ATOMIC_RELAXED, __HIP_MEMORY_SCOPE_AGENT);
    if (t + 1 < TT) {
      int r = tid >> 5, jj = tid & 31, ch = jj >> 2;
      *(u32*)&xt[nxt * 1024 + r * 64 + ((ch ^ (r & 7)) * 8 + (jj & 3) * 2)] = xv;
    }
    asm volatile("s_waitcnt vmcnt(0)" ::: "memory");  // image store drained
    __syncthreads();   // B3
    if (tid == 0 && t + 1 < TT)
      __hip_atomic_store(&cnt[g], (u32)(t + 1), __ATOMIC_RELEASE,
                         __HIP_MEMORY_SCOPE_AGENT);
  }
  {  // epilogue: h_1023 sits in hsw[parity 0] (nxt of t=1023); B3 ordered it
    u64 hv = *(const u64*)&hsw[0 * 2048 + clds];
    *(u64*)(hgp + (size_t)(TT - 1) * 256) = hv;
  }
}

// ---------------- post heads ----------------

__global__ __launch_bounds__(256, 2)
void k_act(const u16* __restrict__ hs, const u16* __restrict__ wafc1,
           const u16* __restrict__ waout, const float* __restrict__ b_afc1,
           const float* __restrict__ b_aout, float* __restrict__ act) {
  __shared__ u16 a_sh[16 * 264];
  __shared__ u16 z_sh[16 * 264];
  __shared__ float sb1[256];
  const int tid = threadIdx.x;
  const int wave = tid >> 6, lane = tid & 63;
  const int l15 = lane & 15, kq = lane >> 4;
  const size_t bt0 = (size_t)blockIdx.x * 16;
  sb1[tid] = b_afc1[tid];
#pragma unroll
  for (int i = 0; i < 2; ++i) {
    int chunk = i * 256 + tid;
    int row = chunk >> 5, c = chunk & 31;
    *(uint4*)&a_sh[row * 264 + c * 8] = *(const uint4*)(hs + (bt0 + row) * 256 + c * 8);
  }
  __syncthreads();
  floatx4 acc[4];
#pragma unroll
  for (int nt = 0; nt < 4; ++nt) acc[nt] = (floatx4){0.f, 0.f, 0.f, 0.f};
#pragma unroll
  for (int kt = 0; kt < 8; ++kt) {
    short8 a = *(const short8*)&a_sh[l15 * 264 + kt * 32 + kq * 8];
#pragma unroll
    for (int nt = 0; nt < 4; ++nt) {
      int n = wave * 64 + nt * 16 + l15;
      short8 b = *(const short8*)(wafc1 + n * 256 + kt * 32 + kq * 8);
      acc[nt] = __builtin_amdgcn_mfma_f32_16x16x32_bf16(a, b, acc[nt], 0, 0, 0);
    }
  }
#pragma unroll
  for (int nt = 0; nt < 4; ++nt) {
    int n = wave * 64 + nt * 16 + l15;
    float bb = sb1[n];
#pragma unroll
    for (int r = 0; r < 4; ++r) {
      float v = acc[nt][r] + bb;
      v = v > 0.f ? v : 0.f;
      z_sh[(kq * 4 + r) * 264 + n] = f2b(v);
    }
  }
  __syncthreads();
  if (wave == 0) {
    floatx4 a2 = (floatx4){0.f, 0.f, 0.f, 0.f};
#pragma unroll
    for (int kt = 0; kt < 8; ++kt) {
      short8 a = *(const short8*)&z_sh[l15 * 264 + kt * 32 + kq * 8];
      short8 b = *(const short8*)(waout + l15 * 256 + kt * 32 + kq * 8);
      a2 = __builtin_amdgcn_mfma_f32_16x16x32_bf16(a, b, a2, 0, 0, 0);
    }
    if (l15 < 8) {
      float bb = b_aout[l15];
#pragma unroll
      for (int r = 0; r < 4; ++r)
        act[(bt0 + (size_t)(kq * 4 + r)) * 8 + l15] = a2[r] + bb;
    }
  }
}

__global__ __launch_bounds__(256, 2)
void k_cb(const u16* __restrict__ hs, const float* __restrict__ x,
          const u16* __restrict__ wcb, const float* __restrict__ b_cont,
          const float* __restrict__ b_bin, float* __restrict__ dout) {
  __shared__ u16 a_sh[16 * 296];
  const int tid = threadIdx.x;
  const int wave = tid >> 6, lane = tid & 63;
  const int l15 = lane & 15, kq = lane >> 4;
  const size_t bt0 = (size_t)blockIdx.x * 16;
#pragma unroll
  for (int i = 0; i < 2; ++i) {
    int chunk = i * 256 + tid;
    int row = chunk >> 5, c = chunk & 31;
    *(uint4*)&a_sh[row * 296 + c * 8] = *(const uint4*)(hs + (bt0 + row) * 256 + c * 8);
  }
  if (tid < 128) {
    int m = tid >> 3, j = tid & 7;
    a_sh[m * 296 + 256 + j] = f2b(x[(bt0 + m) * 43 + 35 + j]);
  }
  for (int i = tid; i < 384; i += 256) {
    int m = i / 24, jj = i % 24;
    a_sh[m * 296 + 264 + jj] = 0;
  }
  __syncthreads();
  const int n = wave * 16 + l15;
  floatx4 acc = (floatx4){0.f, 0.f, 0.f, 0.f};
#pragma unroll
  for (int kt = 0; kt < 9; ++kt) {
    short8 a = *(const short8*)&a_sh[l15 * 296 + kt * 32 + kq * 8];
    short8 b = *(const short8*)(wcb + n * 288 + kt * 32 + kq * 8);
    acc = __builtin_amdgcn_mfma_f32_16x16x32_bf16(a, b, acc, 0, 0, 0);
  }
  if (n < 50) {
    float bb = b_cont[n];
#pragma unroll
    for (int r = 0; r < 4; ++r)
      dout[(bt0 + (size_t)(kq * 4 + r)) * 50 + n] = acc[r] + bb;
  } else if (n < 60) {
    float bb = b_bin[n - 50];
#pragma unroll
    for (int r = 0; r < 4; ++r)
      dout[BIN_OFF + (bt0 + (size_t)(kq * 4 + r)) * 10 + (n - 50)] = sigmf(acc[r] + bb);
  }
}

// ---------------- launch ----------------
extern "C" void kernel_launch(void* const* d_in, const int* in_sizes, int n_in,
                              void* d_out, int out_size, void* d_ws, size_t ws_size,
                              hipStream_t stream) {
  const float* x      = (const float*)d_in[0];
  const float* W_ih   = (const float*)d_in[1];
  const float* W_hh   = (const float*)d_in[2];
  const float* b_ih   = (const float*)d_in[3];
  const float* b_hh   = (const float*)d_in[4];
  const float* W_afc1 = (const float*)d_in[5];
  const float* b_afc1 = (const float*)d_in[6];
  const float* W_aout = (const float*)d_in[7];
  const float* b_aout = (const float*)d_in[8];
  const float* W_cont = (const float*)d_in[9];
  const float* b_cont = (const float*)d_in[10];
  const float* W_bin  = (const float*)d_in[11];
  const float* b_bin  = (const float*)d_in[12];
  float* outf = (float*)d_out;
  char* ws = (char*)d_ws;

  u16*   wcatf  = (u16*)(ws);                    //    655,360 B
  float* bias   = (float*)(ws + 655360);         //      4,096 B
  u16*   wafc1b = (u16*)(ws + 659456);           //    131,072 B
  u16*   waoutb = (u16*)(ws + 790528);           //      8,192 B
  u16*   wcbb   = (u16*)(ws + 798720);           //     36,864 B
  u16*   xchg   = (u16*)(ws + 835584);           //    131,072 B
  u32*   flags  = (u32*)(ws + 966656);           //      4,096 B
  u16*   xin    = (u16*)(ws + 970752);           // 16,777,216 B
  u16*   hs     = (u16*)(ws + 17747968);         // 67,108,864 B (total ~84.9 MB)

  hipLaunchKernelGGL(k_prep_wcatf3, dim3(1280), dim3(256), 0, stream, W_ih, W_hh, wcatf);
  hipLaunchKernelGGL(k_zero_flags, dim3(1), dim3(64), 0, stream, flags);
  hipLaunchKernelGGL(k_prep_bias, dim3(4), dim3(256), 0, stream, b_ih, b_hh, bias);
  hipLaunchKernelGGL(k_prep_afc, dim3(272), dim3(256), 0, stream, W_afc1, W_aout, wafc1b, waoutb);
  hipLaunchKernelGGL(k_prep_wcb, dim3(64), dim3(288), 0, stream, W_cont, W_bin, wcbb);
  hipLaunchKernelGGL(k_prep_xin, dim3(32768), dim3(256), 0, stream, x, xin);
  hipLaunchKernelGGL(k_scan6, dim3(16), dim3(512), 0, stream, wcatf, xin, bias, hs, xchg, flags);
  hipLaunchKernelGGL(k_act, dim3(8192), dim3(256), 0, stream, hs, wafc1b, waoutb, b_afc1, b_aout, outf + ACT_OFF);
  hipLaunchKernelGGL(k_cb, dim3(8192), dim3(256), 0, stream, hs, x, wcbb, b_cont, b_bin, outf);
}